// Round 1
// baseline (194.279 us; speedup 1.0000x reference)
//
#include <hip/hip_runtime.h>
#include <hip/hip_bf16.h>

typedef __attribute__((ext_vector_type(8))) short bf16x8;
typedef __attribute__((ext_vector_type(4))) float f32x4;
typedef __attribute__((ext_vector_type(4))) int i32x4;

// ---------- helpers ----------
static __device__ __forceinline__ void gload_lds16(const void* g, void* l) {
  __builtin_amdgcn_global_load_lds((const __attribute__((address_space(1))) void*)g,
                                   (__attribute__((address_space(3))) void*)l,
                                   16, 0, 0);
}

// f32 -> bf16 bits, round-to-nearest-even
static __device__ __forceinline__ unsigned short f2bf(float x) {
  unsigned int u = __float_as_uint(x);
  u += 0x7fffu + ((u >> 16) & 1u);
  return (unsigned short)(u >> 16);
}

// ---------------- GEMM: C[M,N] = A[M,K](bf16,row-major,lda) x Bt[N,K]^T(bf16,row-major,ldb)
// 128x128 tile, BK=64, 256 threads = 4 waves (2x2), mfma_f32_16x16x32_bf16.
// EPI 0: write f32 C (scores)
// EPI 1: v*=(*fscale); write f32 C and bf16 copy into Cb (ld=ldcb)   [read path]
// EPI 2: sigmoid(v+bias[col]); per-row sum -> atomicAdd rowsum[row]  [gate path]
// EPI 3: write f32 C = v + bias[col]                                  [out proj]
template <int EPI>
__global__ __launch_bounds__(256)
void gemm_bt(const unsigned short* __restrict__ A, int lda,
             const unsigned short* __restrict__ Bt, int ldb,
             int Kd, int Nd,
             float* __restrict__ Cf,
             unsigned short* __restrict__ Cb, int ldcb,
             const float* __restrict__ bias,
             float* __restrict__ rowsum,
             const float* __restrict__ fscale)
{
  __shared__ unsigned short As[128 * 64];
  __shared__ unsigned short Bs[128 * 64];
  const int tid  = threadIdx.x;
  const int wid  = tid >> 6;
  const int lane = tid & 63;
  const int brow = blockIdx.y * 128;
  const int bcol = blockIdx.x * 128;
  const int wr = wid >> 1, wc = wid & 1;
  const int l15 = lane & 15, l4 = lane >> 4;

  f32x4 acc[4][4] = {};

  const int foff = wid * 512 + lane * 8;  // flat bf16 element within tile chunk

  for (int k0 = 0; k0 < Kd; k0 += 64) {
#pragma unroll
    for (int c = 0; c < 4; ++c) {
      int f = c * 2048 + foff;
      int r = f >> 6, kc = f & 63;
      gload_lds16(A + (size_t)(brow + r) * lda + k0 + kc, As + c * 2048 + wid * 512);
    }
#pragma unroll
    for (int c = 0; c < 4; ++c) {
      int f = c * 2048 + foff;
      int r = f >> 6, kc = f & 63;
      gload_lds16(Bt + (size_t)(bcol + r) * ldb + k0 + kc, Bs + c * 2048 + wid * 512);
    }
    __syncthreads();   // compiler drains vmcnt before s_barrier
#pragma unroll
    for (int kk = 0; kk < 2; ++kk) {
      const int ko = kk * 32 + l4 * 8;
      bf16x8 af[4], bfv[4];
#pragma unroll
      for (int m = 0; m < 4; ++m)
        af[m] = *(const bf16x8*)(As + (wr * 64 + m * 16 + l15) * 64 + ko);
#pragma unroll
      for (int n = 0; n < 4; ++n)
        bfv[n] = *(const bf16x8*)(Bs + (wc * 64 + n * 16 + l15) * 64 + ko);
#pragma unroll
      for (int m = 0; m < 4; ++m)
#pragma unroll
        for (int n = 0; n < 4; ++n)
          acc[m][n] = __builtin_amdgcn_mfma_f32_16x16x32_bf16(af[m], bfv[n], acc[m][n], 0, 0, 0);
    }
    __syncthreads();
  }

  // C/D frag mapping (m89-verified): col = lane&15, row = (lane>>4)*4 + j
  if constexpr (EPI == 2) {
#pragma unroll
    for (int m = 0; m < 4; ++m) {
#pragma unroll
      for (int j = 0; j < 4; ++j) {
        float part = 0.0f;
#pragma unroll
        for (int n = 0; n < 4; ++n) {
          int col = bcol + wc * 64 + n * 16 + l15;
          float x = acc[m][n][j] + bias[col];
          part += 1.0f / (1.0f + __expf(-x));
        }
#pragma unroll
        for (int off = 1; off < 16; off <<= 1)
          part += __shfl_xor(part, off, 64);
        if (l15 == 0) {
          int row = brow + wr * 64 + m * 16 + l4 * 4 + j;
          atomicAdd(&rowsum[row], part);
        }
      }
    }
  } else {
    float fs = 1.0f;
    if constexpr (EPI == 1) fs = *fscale;
#pragma unroll
    for (int m = 0; m < 4; ++m) {
      int row0 = brow + wr * 64 + m * 16 + l4 * 4;
#pragma unroll
      for (int n = 0; n < 4; ++n) {
        int col = bcol + wc * 64 + n * 16 + l15;
#pragma unroll
        for (int j = 0; j < 4; ++j) {
          int row = row0 + j;
          float v = acc[m][n][j];
          if constexpr (EPI == 0) {
            Cf[(size_t)row * Nd + col] = v;
          } else if constexpr (EPI == 1) {
            v *= fs;
            Cf[(size_t)row * Nd + col] = v;
            Cb[(size_t)row * ldcb + col] = f2bf(v);
          } else if constexpr (EPI == 3) {
            Cf[(size_t)row * Nd + col] = v + bias[col];
          }
        }
      }
    }
  }
}

// ---------------- softmax over rows of 512: p = softmax(scores/sqrt(128) * w) -> bf16
__global__ __launch_bounds__(256)
void softmax_rows(const float* __restrict__ S, const float* __restrict__ W,
                  unsigned short* __restrict__ P)
{
  const int wid = threadIdx.x >> 6, lane = threadIdx.x & 63;
  const int row = blockIdx.x * 4 + wid;
  const size_t base = (size_t)row * 512 + lane * 8;
  const float sc = 0.08838834764831845f;  // 1/sqrt(128)
  f32x4 s0 = *(const f32x4*)(S + base);
  f32x4 s1 = *(const f32x4*)(S + base + 4);
  f32x4 w0 = *(const f32x4*)(W + base);
  f32x4 w1 = *(const f32x4*)(W + base + 4);
  float v[8];
#pragma unroll
  for (int i = 0; i < 4; ++i) { v[i] = s0[i] * sc * w0[i]; v[4 + i] = s1[i] * sc * w1[i]; }
  float mx = v[0];
#pragma unroll
  for (int i = 1; i < 8; ++i) mx = fmaxf(mx, v[i]);
#pragma unroll
  for (int off = 32; off >= 1; off >>= 1) mx = fmaxf(mx, __shfl_xor(mx, off, 64));
  float sum = 0.0f;
#pragma unroll
  for (int i = 0; i < 8; ++i) { v[i] = __expf(v[i] - mx); sum += v[i]; }
#pragma unroll
  for (int off = 32; off >= 1; off >>= 1) sum += __shfl_xor(sum, off, 64);
  const float inv = 1.0f / sum;
  union { unsigned short u[8]; i32x4 vec; } pk;
#pragma unroll
  for (int i = 0; i < 8; ++i) pk.u[i] = f2bf(v[i] * inv);
  *(i32x4*)(P + base) = pk.vec;
}

// ---------------- f32 -> bf16 convert (8 elems/thread)
__global__ __launch_bounds__(256)
void cvt_bf16x8(const float* __restrict__ in, unsigned short* __restrict__ out, int n8)
{
  int idx = blockIdx.x * 256 + threadIdx.x;
  if (idx >= n8) return;
  size_t f = (size_t)idx * 8;
  f32x4 a = *(const f32x4*)(in + f);
  f32x4 b = *(const f32x4*)(in + f + 4);
  union { unsigned short u[8]; i32x4 vec; } pk;
#pragma unroll
  for (int i = 0; i < 4; ++i) { pk.u[i] = f2bf(a[i]); pk.u[4 + i] = f2bf(b[i]); }
  *(i32x4*)(out + f) = pk.vec;
}

// ---------------- update_input -> cat[:, 1024:2048] bf16
__global__ __launch_bounds__(256)
void cvt_cat_upd(const float* __restrict__ upd, unsigned short* __restrict__ cat)
{
  int idx = blockIdx.x * 256 + threadIdx.x;  // exactly 1048576 threads
  size_t f = (size_t)idx * 8;
  int row = (int)(f >> 10);
  int col = (int)(f & 1023);
  f32x4 a = *(const f32x4*)(upd + f);
  f32x4 b = *(const f32x4*)(upd + f + 4);
  union { unsigned short u[8]; i32x4 vec; } pk;
#pragma unroll
  for (int i = 0; i < 4; ++i) { pk.u[i] = f2bf(a[i]); pk.u[4 + i] = f2bf(b[i]); }
  *(i32x4*)(cat + (size_t)row * 2048 + 1024 + col) = pk.vec;
}

// ---------------- tiled transpose f32[R,C] -> bf16[C,R]
__global__ __launch_bounds__(256)
void transpose_cvt(const float* __restrict__ in, unsigned short* __restrict__ out,
                   int R, int C)
{
  __shared__ float t[32][33];
  const int tx = threadIdx.x & 31, ty = threadIdx.x >> 5;
  const int c0 = blockIdx.x * 32, r0 = blockIdx.y * 32;
#pragma unroll
  for (int i = 0; i < 4; ++i)
    t[ty + i * 8][tx] = in[(size_t)(r0 + ty + i * 8) * C + c0 + tx];
  __syncthreads();
#pragma unroll
  for (int i = 0; i < 4; ++i)
    out[(size_t)(c0 + ty + i * 8) * R + r0 + tx] = f2bf(t[tx][ty + i * 8]);
}

// ---------------- rs = bf16(read_f32 * (1 + gsum[row]/1024))
__global__ __launch_bounds__(256)
void scale_cvt(const float* __restrict__ Rf, const float* __restrict__ gsum,
               unsigned short* __restrict__ Rs)
{
  int idx = blockIdx.x * 256 + threadIdx.x;  // exactly 1048576 threads
  size_t f = (size_t)idx * 8;
  int row = (int)(f >> 10);
  float scl = 1.0f + gsum[row] * (1.0f / 1024.0f);
  f32x4 a = *(const f32x4*)(Rf + f);
  f32x4 b = *(const f32x4*)(Rf + f + 4);
  union { unsigned short u[8]; i32x4 vec; } pk;
#pragma unroll
  for (int i = 0; i < 4; ++i) { pk.u[i] = f2bf(a[i] * scl); pk.u[4 + i] = f2bf(b[i] * scl); }
  *(i32x4*)(Rs + f) = pk.vec;
}

// ---------------- LayerNorm over rows of 1024, block per row
__global__ __launch_bounds__(256)
void ln_rows(const float* __restrict__ X, const float* __restrict__ gamma,
             const float* __restrict__ beta, float* __restrict__ Y)
{
  const int row = blockIdx.x;
  const int tid = threadIdx.x;
  const size_t base = (size_t)row * 1024 + tid * 4;
  f32x4 x = *(const f32x4*)(X + base);
  float s = x[0] + x[1] + x[2] + x[3];
  float q = x[0] * x[0] + x[1] * x[1] + x[2] * x[2] + x[3] * x[3];
#pragma unroll
  for (int off = 32; off >= 1; off >>= 1) {
    s += __shfl_xor(s, off, 64);
    q += __shfl_xor(q, off, 64);
  }
  __shared__ float ss[4], qq[4];
  const int wid = tid >> 6, lane = tid & 63;
  if (lane == 0) { ss[wid] = s; qq[wid] = q; }
  __syncthreads();
  s = ss[0] + ss[1] + ss[2] + ss[3];
  q = qq[0] + qq[1] + qq[2] + qq[3];
  const float mu = s * (1.0f / 1024.0f);
  const float var = q * (1.0f / 1024.0f) - mu * mu;
  const float r = rsqrtf(var + 1e-5f);
  f32x4 g = *(const f32x4*)(gamma + tid * 4);
  f32x4 b = *(const f32x4*)(beta + tid * 4);
  f32x4 y;
#pragma unroll
  for (int i = 0; i < 4; ++i) y[i] = (x[i] - mu) * r * g[i] + b[i];
  *(f32x4*)(Y + base) = y;
}

// ---------------- launch ----------------
extern "C" void kernel_launch(void* const* d_in, const int* in_sizes, int n_in,
                              void* d_out, int out_size, void* d_ws, size_t ws_size,
                              hipStream_t stream)
{
  (void)in_sizes; (void)n_in; (void)out_size; (void)ws_size;
  const float* q   = (const float*)d_in[0];   // [8192,1024]
  const float* mw  = (const float*)d_in[1];   // [8192,512]
  const float* upd = (const float*)d_in[2];   // [8192,1024]
  const float* mk  = (const float*)d_in[3];   // [512,1024]
  const float* mv  = (const float*)d_in[4];   // [512,1024]
  const float* dec = (const float*)d_in[5];   // scalar
  const float* gw  = (const float*)d_in[6];   // [2048,1024]
  const float* gb  = (const float*)d_in[7];   // [1024]
  const float* ow  = (const float*)d_in[8];   // [1024,1024]
  const float* ob  = (const float*)d_in[9];   // [1024]
  const float* lg  = (const float*)d_in[10];  // [1024]
  const float* lb  = (const float*)d_in[11];  // [1024]
  float* outp = (float*)d_out;
  char* ws = (char*)d_ws;

  // workspace layout (bytes); outpre (33.5MB) overlays qb+scores after both are dead
  unsigned short* qb     = (unsigned short*)(ws + 0);          // 16.78 MB
  float*          scores = (float*)(ws + 16777216);            // 16.78 MB
  float*          outpre = (float*)(ws + 0);                   // 33.55 MB (reuse)
  unsigned short* kb     = (unsigned short*)(ws + 33554432);   // 1.05 MB
  unsigned short* vt     = (unsigned short*)(ws + 34603008);   // 1.05 MB
  unsigned short* gwt    = (unsigned short*)(ws + 35651584);   // 4.19 MB
  unsigned short* owt    = (unsigned short*)(ws + 39845888);   // 2.10 MB
  unsigned short* cat    = (unsigned short*)(ws + 41943040);   // 33.55 MB [8192,2048]
  unsigned short* probs  = (unsigned short*)(ws + 75497472);   // 8.39 MB
  float*          readf  = (float*)(ws + 83886080);            // 33.55 MB
  float*          gsum   = (float*)(ws + 117440512);           // 32 KB
  unsigned short* rs     = (unsigned short*)(ws + 117473280);  // 16.78 MB
  // total ~134.3 MB

  // prep: bf16 conversions / transposes
  cvt_bf16x8<<<4096, 256, 0, stream>>>(q, qb, 1048576);
  cvt_bf16x8<<<256, 256, 0, stream>>>(mk, kb, 65536);
  cvt_cat_upd<<<4096, 256, 0, stream>>>(upd, cat);
  transpose_cvt<<<dim3(32, 16), 256, 0, stream>>>(mv, vt, 512, 1024);
  transpose_cvt<<<dim3(32, 64), 256, 0, stream>>>(gw, gwt, 2048, 1024);
  transpose_cvt<<<dim3(32, 32), 256, 0, stream>>>(ow, owt, 1024, 1024);
  hipMemsetAsync(gsum, 0, 8192 * sizeof(float), stream);

  // 1) scores = qb x kb^T   [8192,512], K=1024
  gemm_bt<0><<<dim3(4, 64), 256, 0, stream>>>(qb, 1024, kb, 1024, 1024, 512,
                                              scores, nullptr, 0, nullptr, nullptr, nullptr);
  // 2) probs = softmax(scores/sqrt(128)*w) -> bf16
  softmax_rows<<<2048, 256, 0, stream>>>(scores, mw, probs);
  // 3) read = probs x vt^T * decay; also bf16 into cat[:, :1024]
  gemm_bt<1><<<dim3(8, 64), 256, 0, stream>>>(probs, 512, vt, 512, 512, 1024,
                                              readf, cat, 2048, nullptr, nullptr, dec);
  // 4) gate row-sums: sigmoid(cat x gwt^T + gb) summed per row -> gsum
  gemm_bt<2><<<dim3(8, 64), 256, 0, stream>>>(cat, 2048, gwt, 2048, 2048, 1024,
                                              nullptr, nullptr, 0, gb, gsum, nullptr);
  // 5) rs = bf16(readf * (1 + gsum/1024))
  scale_cvt<<<4096, 256, 0, stream>>>(readf, gsum, rs);
  // 6) outpre = rs x owt^T + ob
  gemm_bt<3><<<dim3(8, 64), 256, 0, stream>>>(rs, 1024, owt, 1024, 1024, 1024,
                                              outpre, nullptr, 0, ob, nullptr, nullptr);
  // 7) LayerNorm -> final output
  ln_rows<<<8192, 256, 0, stream>>>(outpre, lg, lb, outp);
}

// Round 2
// 177.336 us; speedup vs baseline: 1.0955x; 1.0955x over previous
//
#include <hip/hip_runtime.h>
#include <hip/hip_bf16.h>

typedef __attribute__((ext_vector_type(8))) short bf16x8;
typedef __attribute__((ext_vector_type(4))) float f32x4;
typedef __attribute__((ext_vector_type(4))) int i32x4;

// ---------- helpers ----------
static __device__ __forceinline__ void gload_lds16(const void* g, void* l) {
  __builtin_amdgcn_global_load_lds((const __attribute__((address_space(1))) void*)g,
                                   (__attribute__((address_space(3))) void*)l,
                                   16, 0, 0);
}

// f32 -> bf16 bits, round-to-nearest-even
static __device__ __forceinline__ unsigned short f2bf(float x) {
  unsigned int u = __float_as_uint(x);
  u += 0x7fffu + ((u >> 16) & 1u);
  return (unsigned short)(u >> 16);
}

// ---------------- GEMM: C[M,N] = A[M,K](bf16,row-major,lda) x Bt[N,K]^T(bf16,row-major,ldb)
// 128x128 tile, BK=64, 256 threads = 4 waves (2x2), mfma_f32_16x16x32_bf16.
// XCD-aware block swizzle (T1): consecutive logical tiles -> same XCD L2.
// EPI 0: write f32 C (scores)
// EPI 1: v*=(*fscale); write bf16 into Cb (ld=ldcb)                   [read path]
// EPI 2: sigmoid(v+bias[col]); per-row sum -> atomicAdd rowsum[row]   [gate path]
// EPI 3: v = v*(1+rowsum[row]/1024) + bias[col]; write f32 C          [out proj]
template <int EPI>
__global__ __launch_bounds__(256)
void gemm_bt(const unsigned short* __restrict__ A, int lda,
             const unsigned short* __restrict__ Bt, int ldb,
             int Kd, int Nd,
             float* __restrict__ Cf,
             unsigned short* __restrict__ Cb, int ldcb,
             const float* __restrict__ bias,
             float* __restrict__ rowsum,
             const float* __restrict__ fscale)
{
  __shared__ unsigned short As[128 * 64];
  __shared__ unsigned short Bs[128 * 64];
  const int tid  = threadIdx.x;
  const int wid  = tid >> 6;
  const int lane = tid & 63;

  // T1 XCD swizzle (nwg % 8 == 0 for all our launches -> bijective)
  const int nwg  = gridDim.x * gridDim.y;
  const int flat = blockIdx.y * gridDim.x + blockIdx.x;
  const int swz  = (flat & 7) * (nwg >> 3) + (flat >> 3);
  const int bx   = swz % gridDim.x;
  const int by   = swz / gridDim.x;

  const int brow = by * 128;
  const int bcol = bx * 128;
  const int wr = wid >> 1, wc = wid & 1;
  const int l15 = lane & 15, l4 = lane >> 4;

  f32x4 acc[4][4] = {};

  const int foff = wid * 512 + lane * 8;  // flat bf16 element within tile chunk

  for (int k0 = 0; k0 < Kd; k0 += 64) {
#pragma unroll
    for (int c = 0; c < 4; ++c) {
      int f = c * 2048 + foff;
      int r = f >> 6, kc = f & 63;
      gload_lds16(A + (size_t)(brow + r) * lda + k0 + kc, As + c * 2048 + wid * 512);
    }
#pragma unroll
    for (int c = 0; c < 4; ++c) {
      int f = c * 2048 + foff;
      int r = f >> 6, kc = f & 63;
      gload_lds16(Bt + (size_t)(bcol + r) * ldb + k0 + kc, Bs + c * 2048 + wid * 512);
    }
    __syncthreads();   // compiler drains vmcnt before s_barrier
#pragma unroll
    for (int kk = 0; kk < 2; ++kk) {
      const int ko = kk * 32 + l4 * 8;
      bf16x8 af[4], bfv[4];
#pragma unroll
      for (int m = 0; m < 4; ++m)
        af[m] = *(const bf16x8*)(As + (wr * 64 + m * 16 + l15) * 64 + ko);
#pragma unroll
      for (int n = 0; n < 4; ++n)
        bfv[n] = *(const bf16x8*)(Bs + (wc * 64 + n * 16 + l15) * 64 + ko);
#pragma unroll
      for (int m = 0; m < 4; ++m)
#pragma unroll
        for (int n = 0; n < 4; ++n)
          acc[m][n] = __builtin_amdgcn_mfma_f32_16x16x32_bf16(af[m], bfv[n], acc[m][n], 0, 0, 0);
    }
    __syncthreads();
  }

  // C/D frag mapping (m89-verified): col = lane&15, row = (lane>>4)*4 + j
  if constexpr (EPI == 2) {
#pragma unroll
    for (int m = 0; m < 4; ++m) {
#pragma unroll
      for (int j = 0; j < 4; ++j) {
        float part = 0.0f;
#pragma unroll
        for (int n = 0; n < 4; ++n) {
          int col = bcol + wc * 64 + n * 16 + l15;
          float x = acc[m][n][j] + bias[col];
          part += 1.0f / (1.0f + __expf(-x));
        }
#pragma unroll
        for (int off = 1; off < 16; off <<= 1)
          part += __shfl_xor(part, off, 64);
        if (l15 == 0) {
          int row = brow + wr * 64 + m * 16 + l4 * 4 + j;
          atomicAdd(&rowsum[row], part);
        }
      }
    }
  } else {
    float fs = 1.0f;
    if constexpr (EPI == 1) fs = *fscale;
#pragma unroll
    for (int m = 0; m < 4; ++m) {
      int row0 = brow + wr * 64 + m * 16 + l4 * 4;
#pragma unroll
      for (int j = 0; j < 4; ++j) {
        int row = row0 + j;
        float rscl = 0.0f;
        if constexpr (EPI == 3) rscl = 1.0f + rowsum[row] * (1.0f / 1024.0f);
#pragma unroll
        for (int n = 0; n < 4; ++n) {
          int col = bcol + wc * 64 + n * 16 + l15;
          float v = acc[m][n][j];
          if constexpr (EPI == 0) {
            Cf[(size_t)row * Nd + col] = v;
          } else if constexpr (EPI == 1) {
            Cb[(size_t)row * ldcb + col] = f2bf(v * fs);
          } else if constexpr (EPI == 3) {
            Cf[(size_t)row * Nd + col] = v * rscl + bias[col];
          }
        }
      }
    }
  }
}

// ---------------- softmax over rows of 512: p = softmax(scores/sqrt(128) * w) -> bf16
__global__ __launch_bounds__(256)
void softmax_rows(const float* __restrict__ S, const float* __restrict__ W,
                  unsigned short* __restrict__ P)
{
  const int wid = threadIdx.x >> 6, lane = threadIdx.x & 63;
  const int row = blockIdx.x * 4 + wid;
  const size_t base = (size_t)row * 512 + lane * 8;
  const float sc = 0.08838834764831845f;  // 1/sqrt(128)
  f32x4 s0 = *(const f32x4*)(S + base);
  f32x4 s1 = *(const f32x4*)(S + base + 4);
  f32x4 w0 = *(const f32x4*)(W + base);
  f32x4 w1 = *(const f32x4*)(W + base + 4);
  float v[8];
#pragma unroll
  for (int i = 0; i < 4; ++i) { v[i] = s0[i] * sc * w0[i]; v[4 + i] = s1[i] * sc * w1[i]; }
  float mx = v[0];
#pragma unroll
  for (int i = 1; i < 8; ++i) mx = fmaxf(mx, v[i]);
#pragma unroll
  for (int off = 32; off >= 1; off >>= 1) mx = fmaxf(mx, __shfl_xor(mx, off, 64));
  float sum = 0.0f;
#pragma unroll
  for (int i = 0; i < 8; ++i) { v[i] = __expf(v[i] - mx); sum += v[i]; }
#pragma unroll
  for (int off = 32; off >= 1; off >>= 1) sum += __shfl_xor(sum, off, 64);
  const float inv = 1.0f / sum;
  union { unsigned short u[8]; i32x4 vec; } pk;
#pragma unroll
  for (int i = 0; i < 8; ++i) pk.u[i] = f2bf(v[i] * inv);
  *(i32x4*)(P + base) = pk.vec;
}

// ---------------- f32 -> bf16 convert (8 elems/thread)
__global__ __launch_bounds__(256)
void cvt_bf16x8(const float* __restrict__ in, unsigned short* __restrict__ out, int n8)
{
  int idx = blockIdx.x * 256 + threadIdx.x;
  if (idx >= n8) return;
  size_t f = (size_t)idx * 8;
  f32x4 a = *(const f32x4*)(in + f);
  f32x4 b = *(const f32x4*)(in + f + 4);
  union { unsigned short u[8]; i32x4 vec; } pk;
#pragma unroll
  for (int i = 0; i < 4; ++i) { pk.u[i] = f2bf(a[i]); pk.u[4 + i] = f2bf(b[i]); }
  *(i32x4*)(out + f) = pk.vec;
}

// ---------------- update_input -> cat[:, 1024:2048] bf16
__global__ __launch_bounds__(256)
void cvt_cat_upd(const float* __restrict__ upd, unsigned short* __restrict__ cat)
{
  int idx = blockIdx.x * 256 + threadIdx.x;  // exactly 1048576 threads
  size_t f = (size_t)idx * 8;
  int row = (int)(f >> 10);
  int col = (int)(f & 1023);
  f32x4 a = *(const f32x4*)(upd + f);
  f32x4 b = *(const f32x4*)(upd + f + 4);
  union { unsigned short u[8]; i32x4 vec; } pk;
#pragma unroll
  for (int i = 0; i < 4; ++i) { pk.u[i] = f2bf(a[i]); pk.u[4 + i] = f2bf(b[i]); }
  *(i32x4*)(cat + (size_t)row * 2048 + 1024 + col) = pk.vec;
}

// ---------------- tiled transpose f32[R,C] -> bf16[C,R]
__global__ __launch_bounds__(256)
void transpose_cvt(const float* __restrict__ in, unsigned short* __restrict__ out,
                   int R, int C)
{
  __shared__ float t[32][33];
  const int tx = threadIdx.x & 31, ty = threadIdx.x >> 5;
  const int c0 = blockIdx.x * 32, r0 = blockIdx.y * 32;
#pragma unroll
  for (int i = 0; i < 4; ++i)
    t[ty + i * 8][tx] = in[(size_t)(r0 + ty + i * 8) * C + c0 + tx];
  __syncthreads();
#pragma unroll
  for (int i = 0; i < 4; ++i)
    out[(size_t)(c0 + ty + i * 8) * R + r0 + tx] = f2bf(t[tx][ty + i * 8]);
}

// ---------------- LayerNorm over rows of 1024, block per row
__global__ __launch_bounds__(256)
void ln_rows(const float* __restrict__ X, const float* __restrict__ gamma,
             const float* __restrict__ beta, float* __restrict__ Y)
{
  const int row = blockIdx.x;
  const int tid = threadIdx.x;
  const size_t base = (size_t)row * 1024 + tid * 4;
  f32x4 x = *(const f32x4*)(X + base);
  float s = x[0] + x[1] + x[2] + x[3];
  float q = x[0] * x[0] + x[1] * x[1] + x[2] * x[2] + x[3] * x[3];
#pragma unroll
  for (int off = 32; off >= 1; off >>= 1) {
    s += __shfl_xor(s, off, 64);
    q += __shfl_xor(q, off, 64);
  }
  __shared__ float ss[4], qq[4];
  const int wid = tid >> 6, lane = tid & 63;
  if (lane == 0) { ss[wid] = s; qq[wid] = q; }
  __syncthreads();
  s = ss[0] + ss[1] + ss[2] + ss[3];
  q = qq[0] + qq[1] + qq[2] + qq[3];
  const float mu = s * (1.0f / 1024.0f);
  const float var = q * (1.0f / 1024.0f) - mu * mu;
  const float r = rsqrtf(var + 1e-5f);
  f32x4 g = *(const f32x4*)(gamma + tid * 4);
  f32x4 b = *(const f32x4*)(beta + tid * 4);
  f32x4 y;
#pragma unroll
  for (int i = 0; i < 4; ++i) y[i] = (x[i] - mu) * r * g[i] + b[i];
  *(f32x4*)(Y + base) = y;
}

// ---------------- launch ----------------
extern "C" void kernel_launch(void* const* d_in, const int* in_sizes, int n_in,
                              void* d_out, int out_size, void* d_ws, size_t ws_size,
                              hipStream_t stream)
{
  (void)in_sizes; (void)n_in; (void)out_size; (void)ws_size;
  const float* q   = (const float*)d_in[0];   // [8192,1024]
  const float* mw  = (const float*)d_in[1];   // [8192,512]
  const float* upd = (const float*)d_in[2];   // [8192,1024]
  const float* mk  = (const float*)d_in[3];   // [512,1024]
  const float* mv  = (const float*)d_in[4];   // [512,1024]
  const float* dec = (const float*)d_in[5];   // scalar
  const float* gw  = (const float*)d_in[6];   // [2048,1024]
  const float* gb  = (const float*)d_in[7];   // [1024]
  const float* ow  = (const float*)d_in[8];   // [1024,1024]
  const float* ob  = (const float*)d_in[9];   // [1024]
  const float* lg  = (const float*)d_in[10];  // [1024]
  const float* lb  = (const float*)d_in[11];  // [1024]
  float* outp = (float*)d_out;
  char* ws = (char*)d_ws;

  // workspace layout (bytes); outpre (33.5MB) overlays qb+scores after both dead
  unsigned short* qb     = (unsigned short*)(ws + 0);          // 16.78 MB
  float*          scores = (float*)(ws + 16777216);            // 16.78 MB
  float*          outpre = (float*)(ws + 0);                   // 33.55 MB (reuse)
  unsigned short* kb     = (unsigned short*)(ws + 33554432);   // 1.05 MB
  unsigned short* vt     = (unsigned short*)(ws + 34603008);   // 1.05 MB
  unsigned short* gwt    = (unsigned short*)(ws + 35651584);   // 4.19 MB
  unsigned short* owt    = (unsigned short*)(ws + 39845888);   // 2.10 MB
  unsigned short* cat    = (unsigned short*)(ws + 41943040);   // 33.55 MB [8192,2048]
  unsigned short* probs  = (unsigned short*)(ws + 75497472);   // 8.39 MB
  float*          gsum   = (float*)(ws + 83886080);            // 32 KB
  // total ~84 MB

  // prep: bf16 conversions / transposes
  cvt_bf16x8<<<4096, 256, 0, stream>>>(q, qb, 1048576);
  cvt_bf16x8<<<256, 256, 0, stream>>>(mk, kb, 65536);
  cvt_cat_upd<<<4096, 256, 0, stream>>>(upd, cat);
  transpose_cvt<<<dim3(32, 16), 256, 0, stream>>>(mv, vt, 512, 1024);
  transpose_cvt<<<dim3(32, 64), 256, 0, stream>>>(gw, gwt, 2048, 1024);
  transpose_cvt<<<dim3(32, 32), 256, 0, stream>>>(ow, owt, 1024, 1024);
  hipMemsetAsync(gsum, 0, 8192 * sizeof(float), stream);

  // 1) scores = qb x kb^T   [8192,512], K=1024
  gemm_bt<0><<<dim3(4, 64), 256, 0, stream>>>(qb, 1024, kb, 1024, 1024, 512,
                                              scores, nullptr, 0, nullptr, nullptr, nullptr);
  // 2) probs = softmax(scores/sqrt(128)*w) -> bf16
  softmax_rows<<<2048, 256, 0, stream>>>(scores, mw, probs);
  // 3) read = probs x vt^T * decay -> bf16 into cat[:, :1024]
  gemm_bt<1><<<dim3(8, 64), 256, 0, stream>>>(probs, 512, vt, 512, 512, 1024,
                                              nullptr, cat, 2048, nullptr, nullptr, dec);
  // 4) gate row-sums: sigmoid(cat x gwt^T + gb) summed per row -> gsum
  gemm_bt<2><<<dim3(8, 64), 256, 0, stream>>>(cat, 2048, gwt, 2048, 2048, 1024,
                                              nullptr, nullptr, 0, gb, gsum, nullptr);
  // 5) outpre = (read x owt^T)*(1+gsum/1024) + ob   [scale commutes with matmul]
  gemm_bt<3><<<dim3(8, 64), 256, 0, stream>>>(cat, 2048, owt, 1024, 1024, 1024,
                                              outpre, nullptr, 0, ob, gsum, nullptr);
  // 6) LayerNorm -> final output
  ln_rows<<<8192, 256, 0, stream>>>(outpre, lg, lb, outp);
}